// Round 1
// 283.970 us; speedup vs baseline: 1.0172x; 1.0172x over previous
//
#include <hip/hip_runtime.h>
#include <hip/hip_bf16.h>

// KNN_itc: out[b][n] = sum over support descriptors m (441) of top-3 (over 441
// query descriptors) cosine similarities, C=640, bf16 MFMA.
//
// R6 (vs R5):
//  - prep split into norm_kernel + pack_kernel. R5's fused prep used 83KB LDS
//    -> 1 block/CU -> 1 wave/SIMD -> ~130us latency-bound. pack_kernel now
//    runs 2800 blocks with 16.9KB LDS -> 8 blocks/CU (32 waves/CU).
//  - chunk interior reordered to [k-oct][row][kj]: gemm fragment ds_read is
//    lane-linear (lane*16B, contiguous 1KB) -> conflict-free (was +4 cyc/instr,
//    9.24M conflict cycles/dispatch). glds copies linearly so global order ==
//    LDS order; pack_kernel writes the permuted order (still coalesced).
//  - gemm otherwise identical m97-structure: BK=64 slab = 64 chunks (56 A +
//    8 B) staged via global_load_lds width=16, 2 barriers/slab, 10 slabs,
//    in-register top-3 + shuffle merge + one atomicAdd per block.

#define B_IMGS 75
#define N_CLS  5
#define C_DIM  640
#define HW     441
#define HWP    448
#define NKT    20            // 640 / 32 k-chunks
#define NRB    28            // 448 / 16 row-blocks per image
#define CHUNK  512           // 16 rows x 32 k elems = 1 KiB
#define TPAD   66            // pack tile pad: oct-stride = 8*66B*... -> +8 banks

typedef __attribute__((ext_vector_type(8))) short  short8;   // 8 x bf16
typedef __attribute__((ext_vector_type(4))) float  float4v;  // MFMA acc

__device__ __forceinline__ void ins3(float& t0, float& t1, float& t2, float v) {
    float m  = fminf(t0, v);
    t0 = fmaxf(t0, v);
    float m2 = fminf(t1, m);
    t1 = fmaxf(t1, m);
    t2 = fmaxf(t2, m2);
}

__device__ __forceinline__ void glds16(const __hip_bfloat16* g, __hip_bfloat16* l) {
    __builtin_amdgcn_global_load_lds(
        (const __attribute__((address_space(1))) unsigned int*)g,
        (__attribute__((address_space(3))) unsigned int*)l, 16, 0, 0);
}

// ---- P1: L2 norms. block=(img, 64-hw tile); 560 blocks x 256 thr ----
__global__ __launch_bounds__(256)
void norm_kernel(const float* __restrict__ q, const float* __restrict__ S,
                 float* __restrict__ invn) {
    __shared__ float part[4][64];
    int bid = blockIdx.x;
    int img = bid / 7;               // 0..79 (0..74 = q, 75..79 = S)
    int h0  = bid % 7;
    const float* src = (img < B_IMGS)
        ? q + (size_t)img * C_DIM * HW
        : S + (size_t)(img - B_IMGS) * C_DIM * HW;
    int t  = threadIdx.x;
    int hl = t & 63;
    int p  = t >> 6;                 // 160-channel slice
    int hw = h0 * 64 + hl;
    int hwc = (hw < HW) ? hw : (HW - 1);

    float ss = 0.f;
    // manual 16-deep batches: 16 loads in flight per wave
    for (int c0 = p * 160; c0 < (p + 1) * 160; c0 += 16) {
        float v[16];
#pragma unroll
        for (int j = 0; j < 16; ++j) v[j] = src[(size_t)(c0 + j) * HW + hwc];
#pragma unroll
        for (int j = 0; j < 16; ++j) ss += v[j] * v[j];
    }
    part[p][hl] = ss;
    __syncthreads();
    if (t < 64) {
        float tot = part[0][t] + part[1][t] + part[2][t] + part[3][t];
        // pad rows (hw>=441) -> 0 so packed pad descriptors are zeros
        invn[img * HWP + h0 * 64 + t] = (h0 * 64 + t < HW) ? rsqrtf(tot) : 0.f;
    }
}

// ---- P2: normalize + bf16 + fragment-linear chunk writes ----
// block=(img, h0, ktg): 80*7*5 = 2800 blocks x 256 thr; 16.9KB LDS
// chunk layout: elem(row=r16, k32) at oct*128 + r16*8 + (k32&7), oct=k32>>3
//   -> gemm lane l reads elems [l*8, l*8+8): row=l&15, k32=(l>>4)*8+j  (MFMA frag)
__global__ __launch_bounds__(256)
void pack_kernel(const float* __restrict__ q, const float* __restrict__ S,
                 const float* __restrict__ invn,
                 __hip_bfloat16* __restrict__ qn2, __hip_bfloat16* __restrict__ sn2) {
    __shared__ __hip_bfloat16 tile[128][TPAD];   // [c_local][hw_local]
    int bid = blockIdx.x;
    int img = bid / 35;              // 0..79
    int rem = bid % 35;
    int h0  = rem / 5;               // 0..6
    int ktg = rem % 5;               // 0..4 -> channels ktg*128..+127
    const float* src; __hip_bfloat16* dst;
    if (img < B_IMGS) {
        src = q + (size_t)img * C_DIM * HW;
        dst = qn2 + (size_t)img * NRB * NKT * CHUNK;
    } else {
        src = S + (size_t)(img - B_IMGS) * C_DIM * HW;
        dst = sn2 + (size_t)(img - B_IMGS) * NRB * NKT * CHUNK;
    }
    int t  = threadIdx.x;
    int hl = t & 63;
    int p  = t >> 6;                 // 32-channel slice / wave id
    int hw = h0 * 64 + hl;
    int hwc = (hw < HW) ? hw : (HW - 1);
    float iv = invn[img * HWP + h0 * 64 + hl];   // pad rows -> 0

    // stage: 128 c x 64 hw, scaled, single-rounded bf16, [c][hw]
    for (int c0 = p * 32; c0 < p * 32 + 32; c0 += 8) {
        float v[8];
#pragma unroll
        for (int j = 0; j < 8; ++j)
            v[j] = src[(size_t)(ktg * 128 + c0 + j) * HW + hwc];
#pragma unroll
        for (int j = 0; j < 8; ++j)
            tile[c0 + j][hl] = __float2bfloat16(v[j] * iv);
    }
    __syncthreads();

    // pack: wave p owns chunk rb=h0*4+p; lane tl writes bytes [tl*16, tl*16+16)
    int tl  = t & 63;
    int row = tl & 15;
    int oct = tl >> 4;
    int rb  = h0 * 4 + p;
    for (int ktl = 0; ktl < 4; ++ktl) {
        int kt = ktg * 4 + ktl;
        short8 v;
#pragma unroll
        for (int j = 0; j < 8; ++j) {
            // banks: oct -> +8, row pairs share a dword (broadcast): conflict-free
            __hip_bfloat16 hv = tile[ktl * 32 + oct * 8 + j][p * 16 + row];
            v[j] = *(short*)&hv;
        }
        *(short8*)(dst + ((size_t)rb * NKT + kt) * CHUNK + tl * 8) = v;
    }
}

// ------------- gemm + fused top-3: m97-style glds staging -------------
__global__ __launch_bounds__(256, 2)
void gemm_top3_kernel(const __hip_bfloat16* __restrict__ qn2,
                      const __hip_bfloat16* __restrict__ sn2,
                      float* __restrict__ out) {
    __shared__ __hip_bfloat16 sbuf[64 * CHUNK];   // 64 KiB: 56 A + 8 B chunks
    __shared__ float mrg[4][64][3];

    // XCD-grouping swizzle: all 35 (n,mt) blocks of image b on one XCD
    int id  = blockIdx.x;
    int xcd = id & 7;
    int j8  = id >> 3;
    int b   = (j8 / 35) * 8 + xcd;
    if (b >= B_IMGS) return;
    int inner = j8 % 35;
    int n  = inner / 7;
    int mt = inner % 7;

    int tid  = threadIdx.x;
    int w    = tid >> 6;
    int lane = tid & 63;
    int c16  = lane & 15;
    int quad = lane >> 4;
    int frag = lane * 8;   // lane-linear fragment read: conflict-free b128

    const __hip_bfloat16* qA = qn2 + (size_t)b * NRB * NKT * CHUNK;
    const __hip_bfloat16* qB = sn2 + ((size_t)n * NRB + mt * 4) * NKT * CHUNK;

    float4v acc[7][4];
#pragma unroll
    for (int r = 0; r < 7; ++r)
#pragma unroll
        for (int j = 0; j < 4; ++j)
            acc[r][j] = (float4v){0.f, 0.f, 0.f, 0.f};

    for (int s = 0; s < 10; ++s) {
        __syncthreads();                 // prior slab's ds_reads complete
        // stage 64 chunks; wave w moves chunks [w*16, w*16+16)
#pragma unroll
        for (int i = 0; i < 16; ++i) {
            int cid = w * 16 + i;
            const __hip_bfloat16* g;
            if (cid < 56) {
                int rb = cid >> 1;
                g = qA + ((size_t)rb * NKT + 2 * s + (cid & 1)) * CHUNK;
            } else {
                int jb = (cid - 56) >> 1;
                g = qB + ((size_t)jb * NKT + 2 * s + (cid & 1)) * CHUNK;
            }
            glds16(g + lane * 8, sbuf + cid * CHUNK + lane * 8);
        }
        __syncthreads();                 // vmcnt(0)+barrier: staging visible

#pragma unroll
        for (int kk = 0; kk < 2; ++kk) {
            short8 a[7], bfr[4];
#pragma unroll
            for (int r = 0; r < 7; ++r)
                a[r] = *(const short8*)(sbuf + ((r * 4 + w) * 2 + kk) * CHUNK + frag);
#pragma unroll
            for (int j = 0; j < 4; ++j)
                bfr[j] = *(const short8*)(sbuf + (56 + j * 2 + kk) * CHUNK + frag);
#pragma unroll
            for (int r = 0; r < 7; ++r)
#pragma unroll
                for (int j = 0; j < 4; ++j)
                    acc[r][j] = __builtin_amdgcn_mfma_f32_16x16x32_bf16(
                        a[r], bfr[j], acc[r][j], 0, 0, 0);
        }
    }

    // ---- in-register top-3 over this wave's 112 rows, per owned column ----
    float T0[4], T1[4], T2[4];
#pragma unroll
    for (int j = 0; j < 4; ++j) { T0[j] = -1e30f; T1[j] = -1e30f; T2[j] = -1e30f; }
#pragma unroll
    for (int r = 0; r < 7; ++r)
#pragma unroll
        for (int j = 0; j < 4; ++j)
#pragma unroll
            for (int g = 0; g < 4; ++g) {
                int row = r * 64 + w * 16 + quad * 4 + g;   // C layout: row=quad*4+reg
                float v = (row < HW) ? acc[r][j][g] : -1e30f;
                ins3(T0[j], T1[j], T2[j], v);
            }

    // quad-butterfly merge (rows spread over lane bits 4,5)
#pragma unroll
    for (int j = 0; j < 4; ++j) {
#pragma unroll
        for (int d = 16; d <= 32; d <<= 1) {
            float o0 = __shfl_xor(T0[j], d, 64);
            float o1 = __shfl_xor(T1[j], d, 64);
            float o2 = __shfl_xor(T2[j], d, 64);
            ins3(T0[j], T1[j], T2[j], o0);
            ins3(T0[j], T1[j], T2[j], o1);
            ins3(T0[j], T1[j], T2[j], o2);
        }
    }

    // cross-wave merge via LDS
    if (quad == 0) {
#pragma unroll
        for (int j = 0; j < 4; ++j) {
            mrg[w][j * 16 + c16][0] = T0[j];
            mrg[w][j * 16 + c16][1] = T1[j];
            mrg[w][j * 16 + c16][2] = T2[j];
        }
    }
    __syncthreads();
    if (tid < 64) {
        int col = tid;
        float t0 = mrg[0][col][0], t1 = mrg[0][col][1], t2 = mrg[0][col][2];
#pragma unroll
        for (int ww = 1; ww < 4; ++ww) {
            ins3(t0, t1, t2, mrg[ww][col][0]);
            ins3(t0, t1, t2, mrg[ww][col][1]);
            ins3(t0, t1, t2, mrg[ww][col][2]);
        }
        float s = (mt * 64 + col < HW) ? (t0 + t1 + t2) : 0.f;
#pragma unroll
        for (int d = 32; d >= 1; d >>= 1) s += __shfl_xor(s, d, 64);
        if (tid == 0) atomicAdd(&out[b * N_CLS + n], s);
    }
}

extern "C" void kernel_launch(void* const* d_in, const int* in_sizes, int n_in,
                              void* d_out, int out_size, void* d_ws, size_t ws_size,
                              hipStream_t stream) {
    const float* q = (const float*)d_in[0];
    const float* S = (const float*)d_in[1];
    float* out = (float*)d_out;

    char* ws = (char*)d_ws;
    size_t off = 0;
    __hip_bfloat16* qn2 = (__hip_bfloat16*)(ws + off);
    off += (size_t)B_IMGS * NRB * NKT * CHUNK * 2;  off = (off + 255) & ~(size_t)255;
    __hip_bfloat16* sn2 = (__hip_bfloat16*)(ws + off);
    off += (size_t)N_CLS * NRB * NKT * CHUNK * 2;   off = (off + 255) & ~(size_t)255;
    float* invn = (float*)(ws + off);

    hipMemsetAsync(d_out, 0, (size_t)out_size * sizeof(float), stream);

    norm_kernel<<<dim3(80 * 7), dim3(256), 0, stream>>>(q, S, invn);
    pack_kernel<<<dim3(80 * 7 * 5), dim3(256), 0, stream>>>(q, S, invn, qn2, sn2);
    // 8 XCD groups x 350 slots; dead blocks (b>=75) exit immediately
    gemm_top3_kernel<<<dim3(8 * 350), dim3(256), 0, stream>>>(qn2, sn2, out);
}